// Round 1
// baseline (474.067 us; speedup 1.0000x reference)
//
#include <hip/hip_runtime.h>
#include <hip/hip_bf16.h>
#include <math.h>

#define BB 64
#define TT 2048
#define HIDD 256
#define FASTN 64
#define SLOWN 256
#define VOC 64
#define TLOOP (TT - 3)   // 2045 scan steps

// ---------------------------------------------------------------------------
// K1: per-token tables. blocks 0..63: qTok[u] = emb[u] @ Wq + bq (256 thr).
//     block 64: act[v] (gate) and dem[v] (demotion score), threads 0..63.
// ---------------------------------------------------------------------------
__global__ __launch_bounds__(256) void k_tok(
    const float* __restrict__ emb, const float* __restrict__ Wg, const float* __restrict__ bg,
    const float* __restrict__ Wd, const float* __restrict__ bd,
    const float* __restrict__ Wq, const float* __restrict__ bq,
    int* __restrict__ actTok, float* __restrict__ demTok, float* __restrict__ qTok) {
  if (blockIdx.x < 64) {
    int u = blockIdx.x, j = threadIdx.x;
    __shared__ float e[HIDD];
    e[j] = emb[u * HIDD + j];
    __syncthreads();
    float acc = bq[j];
    for (int k = 0; k < HIDD; ++k) acc += e[k] * Wq[k * HIDD + j];
    qTok[u * HIDD + j] = acc;
  } else {
    int v = threadIdx.x;
    if (v < VOC) {
      float g = bg[0], d = bd[0];
      for (int k = 0; k < HIDD; ++k) {
        float e = emb[v * HIDD + k];
        g += e * Wg[k];
        d += e * Wd[k];
      }
      float sig = 1.0f / (1.0f + expf(-g));
      actTok[v] = (sig >= 0.4f) ? 1 : 0;
      demTok[v] = d;
    }
  }
}

// ---------------------------------------------------------------------------
// K2: sequential tiered-memory scan. One wave per batch; lane i = fast slot i.
// State is token ids only. argmin(dem, first-index) = 6-ballot binary search
// over precomputed dem ranks. Slow memory = FIFO ring in LDS.
// ---------------------------------------------------------------------------
__global__ __launch_bounds__(64) void k_scan(
    const int* __restrict__ seq, const int* __restrict__ actTok,
    const float* __restrict__ demTok,
    int* __restrict__ fast_out, int* __restrict__ fcnt_out,
    int* __restrict__ slow_out, int* __restrict__ nslow_out) {
  const int b = blockIdx.x;
  const int lane = threadIdx.x;
  __shared__ int toks[2048];
  __shared__ float demS[64];
  __shared__ int slowS[SLOWN];

  demS[lane] = demTok[lane];
  for (int i = lane; i < SLOWN; i += 64) slowS[i] = -1;
  __syncthreads();

  // rank of token `lane` among dem scores (ascending, ties by token id).
  // Distinct slots holding the same token share a rank; ctz on the ballot
  // candidate mask reproduces jnp.argmin's first-index tie-break.
  float dv = demS[lane];
  int rank = 0;
  for (int u = 0; u < 64; ++u) {
    float du = demS[u];
    rank += (du < dv || (du == dv && u < lane)) ? 1 : 0;
  }

  // preload tokens packed with the act bit (sign bit clear == active)
  for (int t = lane; t < 2048; t += 64) {
    int pkv;
    if (t < TLOOP) {
      int v = seq[b * TT + t];
      pkv = actTok[v] ? v : (v | 0x80000000);
    } else {
      pkv = (int)0x80000000;  // sentinel: inactive
    }
    toks[t] = pkv;
  }
  __syncthreads();

  int mytok = -1;  // token held by my fast slot (-1 = unused)
  int key = 0;     // dem rank of my token
  int fcnt = 0;    // fast slots filled (sequential fill == reference first-free)
  int nslow = 0;   // total slow writes; slot = nslow % 256 (FIFO == argmax(age))

  int pk = toks[0];
  for (int t = 0; t < TLOOP; ++t) {
    int pn = toks[t + 1];  // prefetch (sentinel beyond TLOOP)
    if (pk >= 0) {         // wave-uniform
      int vs = __builtin_amdgcn_readfirstlane(pk);
      int rv = __builtin_amdgcn_readlane(rank, vs);  // rank of incoming token
      if (fcnt < FASTN) {
        bool isme = (lane == fcnt);
        mytok = isme ? vs : mytok;
        key = isme ? rv : key;
        fcnt++;
      } else {
        // argmin over 6-bit keys, lowest lane on ties (MSB-first ballot search)
        unsigned long long cand = ~0ull, z;
        z = __ballot((key & 32) == 0) & cand; if (z) cand = z;
        z = __ballot((key & 16) == 0) & cand; if (z) cand = z;
        z = __ballot((key & 8) == 0) & cand;  if (z) cand = z;
        z = __ballot((key & 4) == 0) & cand;  if (z) cand = z;
        z = __ballot((key & 2) == 0) & cand;  if (z) cand = z;
        z = __ballot((key & 1) == 0) & cand;  if (z) cand = z;
        int fslot = __builtin_ctzll(cand);
        int ss = nslow & (SLOWN - 1);
        nslow++;
        bool isme = (lane == fslot);
        if (isme) slowS[ss] = mytok;  // demote my old token (off critical path)
        mytok = isme ? vs : mytok;
        key = isme ? rv : key;
      }
    }
    pk = pn;
  }
  __syncthreads();

  fast_out[b * FASTN + lane] = mytok;
  for (int i = lane; i < SLOWN; i += 64) slow_out[b * SLOWN + i] = slowS[i];
  if (lane == 0) { fcnt_out[b] = fcnt; nslow_out[b] = nslow; }
}

// ---------------------------------------------------------------------------
// K3: S[v][u] = emb[v] . qTok[u]  (64x64 score table)
// ---------------------------------------------------------------------------
__global__ __launch_bounds__(64) void k_S(
    const float* __restrict__ emb, const float* __restrict__ qTok,
    float* __restrict__ S) {
  int v = blockIdx.x, u = threadIdx.x;
  const float4* e4 = (const float4*)(emb + v * HIDD);
  const float4* q4 = (const float4*)(qTok + u * HIDD);
  float acc = 0.f;
  for (int k = 0; k < HIDD / 4; ++k) {
    float4 a = e4[k], bq_ = q4[k];
    acc += a.x * bq_.x + a.y * bq_.y + a.z * bq_.z + a.w * bq_.w;
  }
  S[v * VOC + u] = acc;
}

// ---------------------------------------------------------------------------
// K4: read head. Per batch: scores via S table -> softmax over 320 ->
// per-token attention mass -> ctx -> logits; plus slow_mask output.
// ---------------------------------------------------------------------------
__global__ __launch_bounds__(256) void k_read(
    const int* __restrict__ seq, const float* __restrict__ emb,
    const float* __restrict__ Wo, const float* __restrict__ bo,
    const float* __restrict__ S,
    const int* __restrict__ fast_tok, const int* __restrict__ fcntA,
    const int* __restrict__ slow_tok, const int* __restrict__ nslowA,
    float* __restrict__ out) {
  int b = blockIdx.x, tid = threadIdx.x;
  __shared__ int mtok[320];
  __shared__ float attn[320];
  __shared__ float wS[64];
  __shared__ float ctxS[HIDD];
  __shared__ float sMax, sSum;

  int fc = fcntA[b];
  int sused = nslowA[b]; if (sused > SLOWN) sused = SLOWN;
  int lastv = seq[b * TT + (TT - 1)];

  if (tid < 64) mtok[tid] = fast_tok[b * FASTN + tid];
  mtok[64 + tid] = slow_tok[b * SLOWN + tid];
  __syncthreads();

  for (int n = tid; n < 320; n += 256) {
    bool used = (n < 64) ? (n < fc) : ((n - 64) < sused);
    attn[n] = used ? S[mtok[n] * VOC + lastv] : -1e9f;
  }
  __syncthreads();

  if (tid < 64) {
    float m = -INFINITY;
    for (int n = tid; n < 320; n += 64) m = fmaxf(m, attn[n]);
    for (int off = 32; off; off >>= 1) m = fmaxf(m, __shfl_xor(m, off));
    if (tid == 0) sMax = m;
  }
  __syncthreads();
  float mx = sMax;
  if (tid < 64) {
    float acc = 0.f;
    for (int n = tid; n < 320; n += 64) {
      float e = expf(attn[n] - mx);
      attn[n] = e;
      acc += e;
    }
    for (int off = 32; off; off >>= 1) acc += __shfl_xor(acc, off);
    if (tid == 0) sSum = acc;
  }
  __syncthreads();
  float inv = 1.0f / sSum;

  // per-token attention mass (exact regroup of ctx = sum attn[n]*emb[tok_n])
  if (tid < 64) {
    float acc = 0.f;
    for (int n = 0; n < 320; ++n) acc += (mtok[n] == tid) ? attn[n] : 0.f;
    wS[tid] = acc * inv;
  }
  __syncthreads();

  float c = 0.f;
  for (int u = 0; u < 64; ++u) c += wS[u] * emb[u * HIDD + tid];
  ctxS[tid] = c;
  __syncthreads();

  if (tid < 64) {
    float acc = bo[tid];
    for (int h = 0; h < HIDD; ++h) acc += ctxS[h] * Wo[h * VOC + tid];
    out[b * VOC + tid] = acc;  // logits
  }
  out[BB * VOC + b * SLOWN + tid] = (tid < sused) ? 1.0f : 0.0f;  // slow_mask
}

// ---------------------------------------------------------------------------
extern "C" void kernel_launch(void* const* d_in, const int* in_sizes, int n_in,
                              void* d_out, int out_size, void* d_ws, size_t ws_size,
                              hipStream_t stream) {
  const int*   seq = (const int*)d_in[0];
  const float* emb = (const float*)d_in[1];
  const float* Wg  = (const float*)d_in[2];
  const float* bg  = (const float*)d_in[3];
  const float* Wd  = (const float*)d_in[4];
  const float* bd  = (const float*)d_in[5];
  const float* Wq  = (const float*)d_in[6];
  const float* bq  = (const float*)d_in[7];
  const float* Wo  = (const float*)d_in[8];
  const float* bo  = (const float*)d_in[9];
  float* out = (float*)d_out;

  char* ws = (char*)d_ws;
  int*   actTok = (int*)(ws + 0 * 4);
  float* demTok = (float*)(ws + 64 * 4);
  float* qTok   = (float*)(ws + 128 * 4);        // 64*256
  float* S      = (float*)(ws + 16512 * 4);      // 64*64
  int*   fastT  = (int*)(ws + 20608 * 4);        // 64*64
  int*   fcntA  = (int*)(ws + 24704 * 4);        // 64
  int*   slowT  = (int*)(ws + 24768 * 4);        // 64*256
  int*   nslowA = (int*)(ws + 41152 * 4);        // 64

  k_tok<<<dim3(65), dim3(256), 0, stream>>>(emb, Wg, bg, Wd, bd, Wq, bq,
                                            actTok, demTok, qTok);
  k_scan<<<dim3(64), dim3(64), 0, stream>>>(seq, actTok, demTok,
                                            fastT, fcntA, slowT, nslowA);
  k_S<<<dim3(64), dim3(64), 0, stream>>>(emb, qTok, S);
  k_read<<<dim3(64), dim3(256), 0, stream>>>(seq, emb, Wo, bo, S,
                                             fastT, fcntA, slowT, nslowA, out);
}

// Round 2
// 284.052 us; speedup vs baseline: 1.6689x; 1.6689x over previous
//
#include <hip/hip_runtime.h>
#include <hip/hip_bf16.h>
#include <math.h>

#define BB 64
#define TT 2048
#define HIDD 256
#define FASTN 64
#define SLOWN 256
#define VOC 64
#define TLOOP (TT - 3)   // 2045 scan steps
#define NEGC -1000000000.0f

// ---------------------------------------------------------------------------
// K1: per-token tables.
//   blocks 0..63 : qTok[u] = emb[u] @ Wq + bq        (256 threads)
//   block 64     : actTok[v] (gate >= 0.4), rankTok[v] = rank of dem score
//                  (ascending, ties by token id; bijection token<->rank)
// ---------------------------------------------------------------------------
__global__ __launch_bounds__(256) void k_tok(
    const float* __restrict__ emb, const float* __restrict__ Wg, const float* __restrict__ bg,
    const float* __restrict__ Wd, const float* __restrict__ bd,
    const float* __restrict__ Wq, const float* __restrict__ bq,
    int* __restrict__ actTok, int* __restrict__ rankTok, float* __restrict__ qTok) {
  if (blockIdx.x < 64) {
    int u = blockIdx.x, j = threadIdx.x;
    __shared__ float e[HIDD];
    e[j] = emb[u * HIDD + j];
    __syncthreads();
    float acc = bq[j];
#pragma unroll 8
    for (int k = 0; k < HIDD; ++k) acc += e[k] * Wq[k * HIDD + j];
    qTok[u * HIDD + j] = acc;
  } else {
    __shared__ float demS[64];
    int v = threadIdx.x;
    if (v < VOC) {
      float g = bg[0], d = bd[0];
#pragma unroll 4
      for (int k = 0; k < HIDD; ++k) {
        float e = emb[v * HIDD + k];
        g += e * Wg[k];
        d += e * Wd[k];
      }
      float sig = 1.0f / (1.0f + expf(-g));
      actTok[v] = (sig >= 0.4f) ? 1 : 0;
      demS[v] = d;
    }
    __syncthreads();
    if (v < VOC) {
      float dv = demS[v];
      int r = 0;
      for (int u = 0; u < 64; ++u) {
        float du = demS[u];
        r += (du < dv || (du == dv && u < v)) ? 1 : 0;
      }
      rankTok[v] = r;
    }
  }
}

// ---------------------------------------------------------------------------
// K2: sequential scan, multiset-of-ranks formulation. One wave per batch.
// Lane r holds cnt = #fast slots whose token has dem-rank r. Per active step:
//   evict rank = ctz(ballot(cnt>0)); insert incoming rank (precomputed).
// Slot assignment provably doesn't affect outputs (read head + masks are
// permutation-invariant over slots), so only the multiset evolves.
// Slow memory = FIFO ring of evicted ranks (aging math collapses to FIFO).
// ---------------------------------------------------------------------------
__global__ __launch_bounds__(64) void k_scan(
    const int* __restrict__ seq, const int* __restrict__ actTok,
    const int* __restrict__ rankTok,
    int* __restrict__ cntAll_out, int* __restrict__ fcnt_out,
    int* __restrict__ nslow_out) {
  const int b = blockIdx.x;
  const int lane = threadIdx.x;
  __shared__ int toks[2080];          // packed: rank of token if active, else -1
  __shared__ int ringS[SLOWN + 64];   // +64 dummy region for predication-free writes
  __shared__ int actS[64], rankS[64], invS[64];

  actS[lane] = actTok[lane];
  int myrank = rankTok[lane];
  rankS[lane] = myrank;
  invS[myrank] = lane;                // rank -> token (bijection)
  __syncthreads();

  for (int t = lane; t < 2080; t += 64) {
    int pkv = -1;
    if (t < TLOOP) {
      int v = seq[b * TT + t];
      pkv = actS[v] ? rankS[v] : -1;
    }
    toks[t] = pkv;
  }
  __syncthreads();

  int cnt = 0;      // count of my rank in fast memory (lane = rank)
  int fcnt = 0;     // fast fill count (uniform, SGPR)
  int nslow = 0;    // total slow writes (uniform)

  int4 c0 = *(const int4*)&toks[0];
  int4 c1 = *(const int4*)&toks[4];
  for (int tb = 0; tb < 2048; tb += 8) {
    int4 n0 = *(const int4*)&toks[tb + 8];
    int4 n1 = *(const int4*)&toks[tb + 12];
#define STEP(PKV)                                                           \
    {                                                                       \
      int pkS = __builtin_amdgcn_readfirstlane(PKV);                        \
      if (pkS >= 0) {                         /* scalar branch */           \
        if (fcnt < FASTN) {                                                 \
          cnt += (lane == pkS) ? 1 : 0;                                     \
          fcnt++;                                                           \
        } else {                                                            \
          unsigned long long bm = __ballot(cnt > 0);                        \
          int rmin = (int)__builtin_ctzll(bm);                              \
          int waddr = (lane == 0) ? (nslow & (SLOWN - 1)) : (SLOWN + lane); \
          ringS[waddr] = rmin;                /* off critical path */       \
          nslow++;                                                          \
          cnt += ((lane == pkS) ? 1 : 0) - ((lane == rmin) ? 1 : 0);        \
        }                                                                   \
      }                                                                     \
    }
    STEP(c0.x) STEP(c0.y) STEP(c0.z) STEP(c0.w)
    STEP(c1.x) STEP(c1.y) STEP(c1.z) STEP(c1.w)
#undef STEP
    c0 = n0; c1 = n1;
  }
  __syncthreads();

  // count my rank in the live ring entries, convert rank->token, emit counts
  int slim = nslow < SLOWN ? nslow : SLOWN;
  int cs = 0;
  for (int i = 0; i < slim; ++i) cs += (ringS[i] == lane) ? 1 : 0;
  int mytok = invS[lane];
  cntAll_out[b * VOC + mytok] = cnt + cs;
  if (lane == 0) { fcnt_out[b] = fcnt; nslow_out[b] = nslow; }
}

// ---------------------------------------------------------------------------
// K3: ST[u][v] = emb[v] . qTok[u]  (query-token-major score table)
// ---------------------------------------------------------------------------
__global__ __launch_bounds__(64) void k_S(
    const float* __restrict__ emb, const float* __restrict__ qTok,
    float* __restrict__ ST) {
  int v = blockIdx.x, u = threadIdx.x;
  const float4* e4 = (const float4*)(emb + v * HIDD);
  const float4* q4 = (const float4*)(qTok + u * HIDD);
  float acc = 0.f;
#pragma unroll 8
  for (int k = 0; k < HIDD / 4; ++k) {
    float4 a = e4[k], bq_ = q4[k];
    acc += a.x * bq_.x + a.y * bq_.y + a.z * bq_.z + a.w * bq_.w;
  }
  ST[u * VOC + v] = acc;
}

// ---------------------------------------------------------------------------
// K4: read head on the token-count representation.
//   w[tok] = cnt[tok] * exp(score - m);  Z = sum w + (320-used)*exp(NEG-m)
//   ctx = sum_tok (w/Z) emb[tok];  logits = ctx@Wo+bo;  slow_mask from nslow.
// Exact regroup of the reference softmax/attention (slots with equal token
// have equal scores; unused slots contribute exp(NEG-m) -> 0).
// ---------------------------------------------------------------------------
__global__ __launch_bounds__(256) void k_read(
    const int* __restrict__ seq, const float* __restrict__ emb,
    const float* __restrict__ Wo, const float* __restrict__ bo,
    const float* __restrict__ ST, const int* __restrict__ cntAll,
    const int* __restrict__ fcntA, const int* __restrict__ nslowA,
    float* __restrict__ out) {
  int b = blockIdx.x, tid = threadIdx.x;
  __shared__ float wS[64];
  __shared__ float ctxS[HIDD];

  int fc = fcntA[b];
  int nslow = nslowA[b];
  int sused = nslow < SLOWN ? nslow : SLOWN;
  int lastv = seq[b * TT + (TT - 1)];

  if (tid < 64) {
    int c = cntAll[b * VOC + tid];
    float sc = ST[lastv * VOC + tid];
    float m = (c > 0) ? sc : NEGC;
    for (int off = 32; off; off >>= 1) m = fmaxf(m, __shfl_xor(m, off));
    float e = (c > 0) ? expf(sc - m) : 0.f;
    float w = (float)c * e;
    float z = w;
    for (int off = 32; off; off >>= 1) z += __shfl_xor(z, off);
    int used = fc + sused;
    z += (float)(FASTN + SLOWN - used) * expf(NEGC - m);  // 0 unless all-masked
    wS[tid] = w / z;
  }
  __syncthreads();

  float c = 0.f;
#pragma unroll 4
  for (int u = 0; u < 64; ++u) c += wS[u] * emb[u * HIDD + tid];
  ctxS[tid] = c;
  __syncthreads();

  if (tid < 64) {
    float acc = bo[tid];
#pragma unroll 4
    for (int h = 0; h < HIDD; ++h) acc += ctxS[h] * Wo[h * VOC + tid];
    out[b * VOC + tid] = acc;  // logits
  }
  out[BB * VOC + b * SLOWN + tid] = (tid < sused) ? 1.0f : 0.0f;  // slow_mask
}

// ---------------------------------------------------------------------------
extern "C" void kernel_launch(void* const* d_in, const int* in_sizes, int n_in,
                              void* d_out, int out_size, void* d_ws, size_t ws_size,
                              hipStream_t stream) {
  const int*   seq = (const int*)d_in[0];
  const float* emb = (const float*)d_in[1];
  const float* Wg  = (const float*)d_in[2];
  const float* bg  = (const float*)d_in[3];
  const float* Wd  = (const float*)d_in[4];
  const float* bd  = (const float*)d_in[5];
  const float* Wq  = (const float*)d_in[6];
  const float* bq  = (const float*)d_in[7];
  const float* Wo  = (const float*)d_in[8];
  const float* bo  = (const float*)d_in[9];
  float* out = (float*)d_out;

  char* ws = (char*)d_ws;
  int*   actTok  = (int*)(ws + 0 * 4);       // 64
  int*   rankTok = (int*)(ws + 64 * 4);      // 64
  float* qTok    = (float*)(ws + 128 * 4);   // 64*256 = 16384
  float* ST      = (float*)(ws + 16512 * 4); // 64*64  = 4096
  int*   cntAll  = (int*)(ws + 20608 * 4);   // 64*64  = 4096
  int*   fcntA   = (int*)(ws + 24704 * 4);   // 64
  int*   nslowA  = (int*)(ws + 24768 * 4);   // 64

  k_tok<<<dim3(65), dim3(256), 0, stream>>>(emb, Wg, bg, Wd, bd, Wq, bq,
                                            actTok, rankTok, qTok);
  k_scan<<<dim3(64), dim3(64), 0, stream>>>(seq, actTok, rankTok,
                                            cntAll, fcntA, nslowA);
  k_S<<<dim3(64), dim3(64), 0, stream>>>(emb, qTok, ST);
  k_read<<<dim3(64), dim3(256), 0, stream>>>(seq, emb, Wo, bo, ST,
                                             cntAll, fcntA, nslowA, out);
}

// Round 3
// 127.746 us; speedup vs baseline: 3.7110x; 2.2236x over previous
//
#include <hip/hip_runtime.h>
#include <math.h>

#define BB 64
#define TT 2048
#define HIDD 256
#define FASTN 64
#define SLOWN 256
#define VOC 64
#define TLOOP (TT - 3)   // 2045 scan steps
#define NEGC -1000000000.0f
#define EPAD 257         // padded emb row stride (bank-conflict-free)

// ---------------------------------------------------------------------------
// Single fused kernel. One block per batch (64 blocks x 256 threads).
//
// Key identity: per rank-threshold k, A_k = #{fast elements with rank <= k}
// evolves as the Lindley queue recurrence  A_k <- max(A_k - 1, 0) + [z <= k]
// (evict-min = decrement lowest-nonzero = decrement A_k for all k with
// A_k > 0). Lane k runs threshold k: two dependent VALU per step, no
// cross-lane ops. Evicted-rank counts for the slow FIFO ring: eviction at
// step j has rank <= k iff A_k(j-1) > 0; accumulate over the last
// min(256, n) steps. Per-rank counts = adjacent differences over lanes.
// Slot permutation is irrelevant (read head + masks are slot-permutation-
// invariant), so token counts fully determine the output.
// ---------------------------------------------------------------------------
__global__ __launch_bounds__(256) void k_fused(
    const int* __restrict__ seq, const float* __restrict__ emb,
    const float* __restrict__ Wg, const float* __restrict__ bg,
    const float* __restrict__ Wd, const float* __restrict__ bd,
    const float* __restrict__ Wq, const float* __restrict__ bq,
    const float* __restrict__ Wo, const float* __restrict__ bo,
    float* __restrict__ out) {
  const int b = blockIdx.x;
  const int tid = threadIdx.x;
  const int lane = tid & 63;

  __shared__ float embS[VOC * EPAD];   // 65792 B
  __shared__ int toksP[2112];          // padded rank stream (idx t + t/32)
  __shared__ int zs[2048];             // compacted active-rank stream
  __shared__ float qS[HIDD];
  __shared__ float ctxS[HIDD];
  __shared__ float gp[4][64], dp[4][64], sp[4][64];
  __shared__ float demS[64], scS[64], wS[64];
  __shared__ int actS[64], rankS[64], invS[64], cntTok[64];
  __shared__ int A_sh, usedS, susedS;

  // ---- stage emb into LDS (coalesced load, padded store) ----
  for (int i = tid; i < VOC * HIDD; i += 256) {
    int v = i >> 8, k = i & 255;
    embS[v * EPAD + k] = emb[i];
  }
  int lastv = seq[b * TT + TT - 1];
  __syncthreads();

  // ---- gate + demotion dots (v = tid&63 so lanes hit distinct banks) ----
  {
    int v = tid & 63, part = tid >> 6;
    const float* er = &embS[v * EPAD + part * 64];
    const float* wgr = &Wg[part * 64];
    const float* wdr = &Wd[part * 64];
    float g = 0.f, d = 0.f;
#pragma unroll 8
    for (int k = 0; k < 64; ++k) {
      float e = er[k];
      g += e * wgr[k];
      d += e * wdr[k];
    }
    gp[part][v] = g; dp[part][v] = d;
  }
  __syncthreads();
  if (tid < 64) {
    float g = gp[0][tid] + gp[1][tid] + gp[2][tid] + gp[3][tid] + bg[0];
    float d = dp[0][tid] + dp[1][tid] + dp[2][tid] + dp[3][tid] + bd[0];
    float sig = 1.f / (1.f + expf(-g));
    actS[tid] = (sig >= 0.4f) ? 1 : 0;
    demS[tid] = d;
  }
  __syncthreads();
  // ---- rank of each token's demotion score (ascending, tie by token id) ----
  if (tid < 64) {
    float dv = demS[tid];
    int r = 0;
    for (int u = 0; u < 64; ++u) {
      float du = demS[u];
      r += (du < dv || (du == dv && u < tid)) ? 1 : 0;
    }
    rankS[tid] = r;
    invS[r] = tid;
  }
  __syncthreads();

  // ---- q = emb[lastv] @ Wq + bq (Wq rows coalesced across threads) ----
  {
    const float* er = &embS[lastv * EPAD];
    float acc = bq[tid];
#pragma unroll 8
    for (int k = 0; k < HIDD; ++k) acc += er[k] * Wq[k * HIDD + tid];
    qS[tid] = acc;
  }
  // ---- stage rank stream (padded layout; holes never read) ----
  for (int t = tid; t < TT; t += 256) {
    int v = seq[b * TT + t];
    int val = (t < TLOOP && actS[v]) ? rankS[v] : -1;
    toksP[t + (t >> 5)] = val;
  }
  __syncthreads();

  // ---- scores sc[v] = emb[v] . q ----
  {
    int v = tid & 63, part = tid >> 6;
    const float* er = &embS[v * EPAD + part * 64];
    const float* qr = &qS[part * 64];
    float s = 0.f;
#pragma unroll 8
    for (int k = 0; k < 64; ++k) s += er[k] * qr[k];
    sp[part][v] = s;
  }
  __syncthreads();
  if (tid < 64) scS[tid] = sp[0][tid] + sp[1][tid] + sp[2][tid] + sp[3][tid];

  // ---- wave 0: compact actives (order-preserving) ----
  if (tid < 64) {
    const int base = lane * 33;  // lane's 32-token chunk, padded stride
    int c = 0;
#pragma unroll 8
    for (int j = 0; j < 32; ++j) c += (toksP[base + j] >= 0) ? 1 : 0;
    int incl = c;
    for (int d = 1; d < 64; d <<= 1) {
      int t = __shfl_up(incl, d);
      if (lane >= d) incl += t;
    }
    int pos = incl - c;  // exclusive prefix
#pragma unroll 4
    for (int j = 0; j < 32; ++j) {
      int z = toksP[base + j];
      if (z >= 0) zs[pos++] = z;
    }
    if (lane == 63) A_sh = incl;
  }
  __syncthreads();

  // ---- wave 0: Lindley scan (lane = rank threshold) ----
  if (tid < 64) {
    const int A = A_sh;
    const int fill = A < 64 ? A : 64;
    const int n = A - fill;              // LRU-phase steps = slow writes
    const int win = n < 256 ? n : 256;   // live ring entries
    const int wstart = 64 + (n - win);   // zs index where ring window begins

    int a = 0;  // A_lane after fill phase
    for (int i = 0; i < fill; ++i) a += (zs[i] <= lane) ? 1 : 0;

    int e = 0;
#pragma unroll 4
    for (int i = 64; i < wstart; ++i) {
      int z = zs[i];
      int x = (z <= lane) ? 1 : 0;
      a = max(a + x - 1, x);             // evict-min + insert, per threshold
    }
#pragma unroll 4
    for (int i = wstart; i < A; ++i) {
      int z = zs[i];
      e += (a > 0) ? 1 : 0;              // eviction rank <= lane ?
      int x = (z <= lane) ? 1 : 0;
      a = max(a + x - 1, x);
    }

    int ap = __shfl_up(a, 1); if (lane == 0) ap = 0;
    int ep = __shfl_up(e, 1); if (lane == 0) ep = 0;
    cntTok[invS[lane]] = (a - ap) + (e - ep);  // fast + slow count of my rank
    if (lane == 0) { usedS = fill + win; susedS = win; }
  }
  __syncthreads();

  // ---- softmax over token counts (exact regroup of 320-slot softmax) ----
  if (tid < 64) {
    int c = cntTok[tid];
    float sc = scS[tid];
    float m = (c > 0) ? sc : NEGC;
    for (int off = 32; off; off >>= 1) m = fmaxf(m, __shfl_xor(m, off));
    float w = (c > 0) ? (float)c * expf(sc - m) : 0.f;
    float z = w;
    for (int off = 32; off; off >>= 1) z += __shfl_xor(z, off);
    z += (float)(FASTN + SLOWN - usedS) * expf(NEGC - m);  // 0 unless empty
    wS[tid] = w / z;
  }
  __syncthreads();

  // ---- ctx[h] = sum_u wS[u] * emb[u][h] ----
  {
    float c = 0.f;
#pragma unroll 8
    for (int u = 0; u < 64; ++u) c += wS[u] * embS[u * EPAD + tid];
    ctxS[tid] = c;
  }
  __syncthreads();

  // ---- logits + slow_mask ----
  if (tid < 64) {
    float acc = bo[tid];
#pragma unroll 8
    for (int h = 0; h < HIDD; ++h) acc += ctxS[h] * Wo[h * VOC + tid];
    out[b * VOC + tid] = acc;
  }
  out[BB * VOC + b * SLOWN + tid] = (tid < susedS) ? 1.0f : 0.0f;
}

// ---------------------------------------------------------------------------
extern "C" void kernel_launch(void* const* d_in, const int* in_sizes, int n_in,
                              void* d_out, int out_size, void* d_ws, size_t ws_size,
                              hipStream_t stream) {
  const int*   seq = (const int*)d_in[0];
  const float* emb = (const float*)d_in[1];
  const float* Wg  = (const float*)d_in[2];
  const float* bg  = (const float*)d_in[3];
  const float* Wd  = (const float*)d_in[4];
  const float* bd  = (const float*)d_in[5];
  const float* Wq  = (const float*)d_in[6];
  const float* bq  = (const float*)d_in[7];
  const float* Wo  = (const float*)d_in[8];
  const float* bo  = (const float*)d_in[9];
  float* out = (float*)d_out;

  k_fused<<<dim3(64), dim3(256), 0, stream>>>(seq, emb, Wg, bg, Wd, bd,
                                              Wq, bq, Wo, bo, out);
}

// Round 4
// 121.218 us; speedup vs baseline: 3.9108x; 1.0538x over previous
//
#include <hip/hip_runtime.h>
#include <math.h>

#define BB 64
#define TT 2048
#define HIDD 256
#define FASTN 64
#define SLOWN 256
#define VOC 64
#define TLOOP (TT - 3)   // 2045 scan steps
#define NEGC -1000000000.0f
#define EPAD 257         // padded emb row stride (bank-conflict-free)

// ---------------------------------------------------------------------------
// One fused kernel, one block per batch (64 x 256).
// Scan = per-rank-threshold Lindley recurrence (lane k: a <- max(a+x-1, x),
// x = [z <= k]); slow ring = eviction count over last min(n,256) LRU steps
// (e += [a>0] pre-update). Token counts = adjacent lane differences.
// Wave 0 runs compact+scan (byte-packed stream, ds_read_b128 per 16 steps,
// prefetched); waves 1-3 concurrently compute q = emb[last]@Wq + bq and
// prefetch Wo into LDS. Epilogue: softmax regroup over 64 token counts.
// ---------------------------------------------------------------------------
__global__ __launch_bounds__(256) void k_all(
    const int* __restrict__ seq, const float* __restrict__ emb,
    const float* __restrict__ Wg, const float* __restrict__ bg,
    const float* __restrict__ Wd, const float* __restrict__ bd,
    const float* __restrict__ Wq, const float* __restrict__ bq,
    const float* __restrict__ Wo, const float* __restrict__ bo,
    float* __restrict__ out) {
  const int b = blockIdx.x;
  const int tid = threadIdx.x;
  const int lane = tid & 63;

  __shared__ float embS[VOC * EPAD];                    // 65792 B
  __shared__ float WoS[HIDD * VOC];                     // 65536 B
  __shared__ int seqS[TT];                              // 8192 B
  __shared__ __align__(16) unsigned char toksB[TT];     // 2048 B
  __shared__ __align__(16) unsigned char zsB[TT + 32];  // 2080 B
  __shared__ float qS[HIDD], ctxS[HIDD];
  __shared__ float pp[4][64], dpp[4][64];
  __shared__ float demS[64], wS[64];
  __shared__ int actS[64], rankS[64], invS[64], cntTok[64];
  __shared__ int usedSh, susedSh;

  const int lastv = seq[b * TT + TT - 1];

  // ---- P0: stage emb (padded) + seq ----
  for (int i = tid; i < VOC * HIDD; i += 256)
    embS[(i >> 8) * EPAD + (i & 255)] = emb[i];
  for (int t = tid; t < TT; t += 256) seqS[t] = seq[b * TT + t];
  __syncthreads();

  // ---- P1: gate/demotion partial dots ----
  {
    int v = tid & 63, part = tid >> 6;
    const float* er = &embS[v * EPAD + part * 64];
    const float* wg = &Wg[part * 64];
    const float* wd = &Wd[part * 64];
    float g = 0.f, d = 0.f;
#pragma unroll 8
    for (int k = 0; k < 64; ++k) { float e = er[k]; g += e * wg[k]; d += e * wd[k]; }
    pp[part][v] = g; dpp[part][v] = d;
  }
  __syncthreads();

  // ---- P2: act/dem combine, then rank (ascending dem, ties by token id) ----
  if (tid < 64) {
    float g = pp[0][tid] + pp[1][tid] + pp[2][tid] + pp[3][tid] + bg[0];
    float d = dpp[0][tid] + dpp[1][tid] + dpp[2][tid] + dpp[3][tid] + bd[0];
    actS[tid] = (1.f / (1.f + expf(-g)) >= 0.4f) ? 1 : 0;
    demS[tid] = d;
  }
  __syncthreads();
  if (tid < 64) {
    float dv = demS[tid];
    int r = 0;
    for (int u = 0; u < 64; ++u) {
      float du = demS[u];
      r += (du < dv || (du == dv && u < tid)) ? 1 : 0;
    }
    rankS[tid] = r; invS[r] = tid;
  }
  __syncthreads();

  // ---- P3: byte-packed rank stream (0xFF = inactive/skip) ----
  {
    int base = tid * 8;
    unsigned int u0 = 0, u1 = 0;
#pragma unroll
    for (int j = 0; j < 4; ++j) {
      int t = base + j; int v = seqS[t];
      unsigned int by = (t < TLOOP && actS[v]) ? (unsigned)rankS[v] : 0xFFu;
      u0 |= by << (8 * j);
    }
#pragma unroll
    for (int j = 0; j < 4; ++j) {
      int t = base + 4 + j; int v = seqS[t];
      unsigned int by = (t < TLOOP && actS[v]) ? (unsigned)rankS[v] : 0xFFu;
      u1 |= by << (8 * j);
    }
    ((uint2*)toksB)[tid] = make_uint2(u0, u1);
  }
  __syncthreads();

  // ================= P4: wave0 scan  ||  waves1-3 q + Wo prefetch ==========
  if (tid < 64) {
    // ---- compact actives (order-preserving), byte output ----
    const uint4 wA = *((const uint4*)(toksB + lane * 32));
    const uint4 wB = *((const uint4*)(toksB + lane * 32 + 16));
    unsigned int dw[8] = {wA.x, wA.y, wA.z, wA.w, wB.x, wB.y, wB.z, wB.w};
    int c = 0;
#pragma unroll
    for (int d = 0; d < 8; ++d)
#pragma unroll
      for (int j = 0; j < 4; ++j)
        c += (((dw[d] >> (8 * j)) & 0xFFu) != 0xFFu) ? 1 : 0;
    int incl = c;
    for (int s = 1; s < 64; s <<= 1) {
      int t = __shfl_up(incl, s);
      if (lane >= s) incl += t;
    }
    int pos = incl - c;
#pragma unroll
    for (int d = 0; d < 8; ++d)
#pragma unroll
      for (int j = 0; j < 4; ++j) {
        unsigned int z = (dw[d] >> (8 * j)) & 0xFFu;
        if (z != 0xFFu) zsB[pos++] = (unsigned char)z;
      }
    const int A = __shfl(incl, 63);

    const int fillN = A < 64 ? A : 64;
    const int n = A - fillN;
    const int win = n < 256 ? n : 256;
    const int wstart = A - win;      // first windowed (e-counted) step

    int a = 0, e = 0;
    const uint4* zs4 = (const uint4*)zsB;

    if (A >= 64) {
      // fill: steps [0,64), a += x
#pragma unroll
      for (int g = 0; g < 4; ++g) {
        uint4 q4 = zs4[g];
        unsigned int ds[4] = {q4.x, q4.y, q4.z, q4.w};
#pragma unroll
        for (int d = 0; d < 4; ++d)
#pragma unroll
          for (int j = 0; j < 4; ++j) {
            int z = (int)((ds[d] >> (8 * j)) & 0xFFu);
            a += (z <= lane) ? 1 : 0;
          }
      }
      // LRU steps [64, A) in 16-step groups with prefetch; per-group mode:
      //   MAIN (fully < wstart): no e.  WIN (fully in [wstart,A)): e pre-update.
      //   GATED (boundary): per-step uniform gates.
      uint4 cur = zs4[4];
      for (int g = 4; g * 16 < A; ++g) {
        uint4 nxt = zs4[g + 1];  // zsB has +32 pad; overrun bytes never used
        const int gs = g * 16;
        unsigned int ds[4] = {cur.x, cur.y, cur.z, cur.w};
        if (gs + 16 <= wstart) {            // MAIN
#pragma unroll
          for (int d = 0; d < 4; ++d)
#pragma unroll
            for (int j = 0; j < 4; ++j) {
              int z = (int)((ds[d] >> (8 * j)) & 0xFFu);
              int x = (z <= lane) ? 1 : 0;
              a = max(a + x - 1, x);
            }
        } else if (gs >= wstart && gs + 16 <= A) {   // WIN
#pragma unroll
          for (int d = 0; d < 4; ++d)
#pragma unroll
            for (int j = 0; j < 4; ++j) {
              int z = (int)((ds[d] >> (8 * j)) & 0xFFu);
              int x = (z <= lane) ? 1 : 0;
              e += (a > 0) ? 1 : 0;
              a = max(a + x - 1, x);
            }
        } else {                                     // GATED boundary group
#pragma unroll
          for (int d = 0; d < 4; ++d)
#pragma unroll
            for (int j = 0; j < 4; ++j) {
              int i = gs + d * 4 + j;
              int z = (int)((ds[d] >> (8 * j)) & 0xFFu);
              int x = (z <= lane) ? 1 : 0;
              bool vld = i < A;
              bool cg = (i >= wstart) && vld;
              e += (cg && a > 0) ? 1 : 0;
              int an = max(a + x - 1, x);
              a = vld ? an : a;
            }
        }
        cur = nxt;
      }
    } else {
      for (int i = 0; i < A; ++i) {
        int z = zsB[i];
        a += (z <= lane) ? 1 : 0;
      }
    }

    int ap = __shfl_up(a, 1); if (lane == 0) ap = 0;
    int ep = __shfl_up(e, 1); if (lane == 0) ep = 0;
    cntTok[invS[lane]] = (a - ap) + (e - ep);
    if (lane == 0) { usedSh = fillN + win; susedSh = win; }
  } else {
    // ---- waves 1-3: q[j] = emb[last] @ Wq[:,j] + bq[j]; Wo -> LDS ----
    const float* eL = &embS[lastv * EPAD];
    {
      int j = tid - 64;
      float a0 = 0, a1 = 0, a2 = 0, a3 = 0;
#pragma unroll 4
      for (int k = 0; k < HIDD; k += 4) {
        a0 += eL[k]     * Wq[(k)     * HIDD + j];
        a1 += eL[k + 1] * Wq[(k + 1) * HIDD + j];
        a2 += eL[k + 2] * Wq[(k + 2) * HIDD + j];
        a3 += eL[k + 3] * Wq[(k + 3) * HIDD + j];
      }
      qS[j] = (a0 + a1) + (a2 + a3) + bq[j];
    }
    if (tid < 128) {   // wave 1 also covers j in [192,256)
      int j = tid + 128;
      float a0 = 0, a1 = 0, a2 = 0, a3 = 0;
#pragma unroll 4
      for (int k = 0; k < HIDD; k += 4) {
        a0 += eL[k]     * Wq[(k)     * HIDD + j];
        a1 += eL[k + 1] * Wq[(k + 1) * HIDD + j];
        a2 += eL[k + 2] * Wq[(k + 2) * HIDD + j];
        a3 += eL[k + 3] * Wq[(k + 3) * HIDD + j];
      }
      qS[j] = (a0 + a1) + (a2 + a3) + bq[j];
    } else {           // waves 2-3: prefetch Wo
      for (int i = tid - 128; i < HIDD * VOC; i += 128) WoS[i] = Wo[i];
    }
  }
  __syncthreads();

  // ---- P5: scores sc[v] = emb[v].q, then softmax regroup over counts ----
  {
    int v = tid & 63, part = tid >> 6;
    const float* er = &embS[v * EPAD + part * 64];
    const float* qr = &qS[part * 64];
    float s = 0.f;
#pragma unroll 8
    for (int k = 0; k < 64; ++k) s += er[k] * qr[k];
    pp[part][v] = s;
  }
  __syncthreads();
  if (tid < 64) {
    float sc = pp[0][tid] + pp[1][tid] + pp[2][tid] + pp[3][tid];
    int c = cntTok[tid];
    float m = (c > 0) ? sc : NEGC;
    for (int off = 32; off; off >>= 1) m = fmaxf(m, __shfl_xor(m, off));
    float w = (c > 0) ? (float)c * expf(sc - m) : 0.f;
    float z = w;
    for (int off = 32; off; off >>= 1) z += __shfl_xor(z, off);
    z += (float)(FASTN + SLOWN - usedSh) * expf(NEGC - m);  // 0 unless empty
    wS[tid] = w / z;
  }
  __syncthreads();

  // ---- P6: ctx[h] = sum_u wS[u] * emb[u][h] ----
  {
    float cacc = 0.f;
#pragma unroll 8
    for (int u = 0; u < 64; ++u) cacc += wS[u] * embS[u * EPAD + tid];
    ctxS[tid] = cacc;
  }
  __syncthreads();

  // ---- P7: logits = ctx @ Wo + bo (partials over 4 h-quarters) ----
  {
    int o = tid & 63, part = tid >> 6;
    const float* cr = &ctxS[part * 64];
    const float* wr = &WoS[part * 64 * VOC + o];
    float s = 0.f;
#pragma unroll 8
    for (int k = 0; k < 64; ++k) s += cr[k] * wr[k * VOC];
    pp[part][o] = s;
  }
  __syncthreads();
  if (tid < 64)
    out[b * VOC + tid] = pp[0][tid] + pp[1][tid] + pp[2][tid] + pp[3][tid] + bo[tid];
  out[BB * VOC + b * SLOWN + tid] = (tid < susedSh) ? 1.0f : 0.0f;
}

// ---------------------------------------------------------------------------
extern "C" void kernel_launch(void* const* d_in, const int* in_sizes, int n_in,
                              void* d_out, int out_size, void* d_ws, size_t ws_size,
                              hipStream_t stream) {
  const int*   seq = (const int*)d_in[0];
  const float* emb = (const float*)d_in[1];
  const float* Wg  = (const float*)d_in[2];
  const float* bg  = (const float*)d_in[3];
  const float* Wd  = (const float*)d_in[4];
  const float* bd  = (const float*)d_in[5];
  const float* Wq  = (const float*)d_in[6];
  const float* bq  = (const float*)d_in[7];
  const float* Wo  = (const float*)d_in[8];
  const float* bo  = (const float*)d_in[9];
  float* out = (float*)d_out;

  k_all<<<dim3(64), dim3(256), 0, stream>>>(seq, emb, Wg, bg, Wd, bd,
                                            Wq, bq, Wo, bo, out);
}

// Round 5
// 115.238 us; speedup vs baseline: 4.1138x; 1.0519x over previous
//
#include <hip/hip_runtime.h>
#include <math.h>

#define BB 64
#define TT 2048
#define HIDD 256
#define FASTN 64
#define SLOWN 256
#define VOC 64
#define TLOOP (TT - 3)   // 2045 scan steps
#define NEGC -1000000000.0f
#define EPAD 257         // padded emb row stride (bank-conflict-free)

// ---------------------------------------------------------------------------
// One fused kernel, one block per batch (64 x 256).
// Scan: per-rank-threshold Lindley recurrence, lane k:
//   a <- max(a,1) + xm1,   xm1 = [z<=k] - 1   (== max(a+x-1, x), 2-VALU chain)
// Slow ring = eviction count e += [a>0] over the last min(n,256) LRU steps.
// Token counts = adjacent lane differences of (a, e). Slot permutation is
// output-invariant, so counts fully determine logits + masks.
// Overlap region: wave0 compact+scan, waves1-2 q=emb[last]@Wq+bq (2 cols each,
// interleaved), wave3 stages Wo. seq held in registers from kernel entry.
// ---------------------------------------------------------------------------
__global__ __launch_bounds__(256) void k_all(
    const int* __restrict__ seq, const float* __restrict__ emb,
    const float* __restrict__ Wg, const float* __restrict__ bg,
    const float* __restrict__ Wd, const float* __restrict__ bd,
    const float* __restrict__ Wq, const float* __restrict__ bq,
    const float* __restrict__ Wo, const float* __restrict__ bo,
    float* __restrict__ out) {
  const int b = blockIdx.x;
  const int tid = threadIdx.x;
  const int lane = tid & 63;

  __shared__ float embS[VOC * EPAD];                    // 65792 B
  __shared__ float WoS[HIDD * VOC];                     // 65536 B
  __shared__ __align__(16) unsigned char toksB[TT];     // 2048 B
  __shared__ __align__(16) unsigned char zsB[TT + 32];  // 2080 B
  __shared__ float qS[HIDD], ctxS[HIDD];
  __shared__ float pp[4][64], dpp[4][64];
  __shared__ float demS[64], wS[64];
  __shared__ int prS[64], invS[64], cntTok[64];
  __shared__ int usedSh, susedSh;

  // ---- entry: issue seq loads into registers (consumed at P3) ----
  const int4* seq4 = (const int4*)(seq + b * TT);
  const int4 sq0 = seq4[tid];          // tokens t = 4*tid .. 4*tid+3
  const int4 sq1 = seq4[tid + 256];    // tokens t = 1024+4*tid ..
  const int lastv = seq[b * TT + TT - 1];

  // ---- P0: stage emb (float4 loads, padded scalar stores) ----
  const float4* emb4 = (const float4*)emb;
  for (int i = tid; i < VOC * 64; i += 256) {
    float4 e = emb4[i];
    float* d = &embS[(i >> 6) * EPAD + ((i & 63) << 2)];
    d[0] = e.x; d[1] = e.y; d[2] = e.z; d[3] = e.w;
  }
  __syncthreads();

  // ---- P1: gate/demotion partial dots ----
  {
    int v = tid & 63, part = tid >> 6;
    const float* er = &embS[v * EPAD + part * 64];
    const float* wg = &Wg[part * 64];
    const float* wd = &Wd[part * 64];
    float g = 0.f, d = 0.f;
#pragma unroll 8
    for (int k = 0; k < 64; ++k) { float e = er[k]; g += e * wg[k]; d += e * wd[k]; }
    pp[part][v] = g; dpp[part][v] = d;
  }
  __syncthreads();

  // ---- P2: combine -> act/dem; then rank (ascending dem, tie by token id) ----
  int myact = 0;
  if (tid < 64) {
    float g = pp[0][tid] + pp[1][tid] + pp[2][tid] + pp[3][tid] + bg[0];
    float d = dpp[0][tid] + dpp[1][tid] + dpp[2][tid] + dpp[3][tid] + bd[0];
    myact = (1.f / (1.f + expf(-g)) >= 0.4f) ? 1 : 0;
    demS[tid] = d;
  }
  __syncthreads();
  if (tid < 64) {
    float dv = demS[tid];
    int r = 0;
    for (int u = 0; u < 64; ++u) {
      float du = demS[u];
      r += (du < dv || (du == dv && u < tid)) ? 1 : 0;
    }
    prS[tid] = myact ? r : 0xFF;   // packed act+rank
    invS[r] = tid;
  }
  __syncthreads();

  // ---- P3: byte-packed rank stream from registers (0xFF = skip) ----
  {
    int t0 = tid * 4;
    int ta[4] = {sq0.x, sq0.y, sq0.z, sq0.w};
    int tb[4] = {sq1.x, sq1.y, sq1.z, sq1.w};
    unsigned u0 = 0, u1 = 0;
#pragma unroll
    for (int j = 0; j < 4; ++j) {
      unsigned byA = (t0 + j < TLOOP) ? (unsigned)prS[ta[j]] : 0xFFu;
      unsigned byB = (1024 + t0 + j < TLOOP) ? (unsigned)prS[tb[j]] : 0xFFu;
      u0 |= byA << (8 * j);
      u1 |= byB << (8 * j);
    }
    ((unsigned*)toksB)[tid] = u0;
    ((unsigned*)toksB)[tid + 256] = u1;
  }
  __syncthreads();

  // ================= P4: wave0 scan || waves1-2 q || wave3 Wo ==============
  if (tid < 64) {
    // ---- compact actives (order-preserving), byte output ----
    const uint4 wA = *((const uint4*)(toksB + lane * 32));
    const uint4 wB = *((const uint4*)(toksB + lane * 32 + 16));
    unsigned int dw[8] = {wA.x, wA.y, wA.z, wA.w, wB.x, wB.y, wB.z, wB.w};
    int c = 0;
#pragma unroll
    for (int d = 0; d < 8; ++d)
#pragma unroll
      for (int j = 0; j < 4; ++j)
        c += (((dw[d] >> (8 * j)) & 0xFFu) != 0xFFu) ? 1 : 0;
    int incl = c;
    for (int s = 1; s < 64; s <<= 1) {
      int t = __shfl_up(incl, s);
      if (lane >= s) incl += t;
    }
    int pos = incl - c;
#pragma unroll
    for (int d = 0; d < 8; ++d)
#pragma unroll
      for (int j = 0; j < 4; ++j) {
        unsigned int z = (dw[d] >> (8 * j)) & 0xFFu;
        if (z != 0xFFu) zsB[pos++] = (unsigned char)z;
      }
    const int A = __builtin_amdgcn_readfirstlane(__shfl(incl, 63));

    const int fillN = A < 64 ? A : 64;
    const int n = A - fillN;
    const int win = n < 256 ? n : 256;
    const int wstart = A - win;      // first e-counted step

    int a = 0, e = 0;
    const uint4* zs4 = (const uint4*)zsB;

    if (A >= 64) {
      // fill: steps [0,64)
#pragma unroll
      for (int g = 0; g < 4; ++g) {
        uint4 q4 = zs4[g];
        unsigned int ds[4] = {q4.x, q4.y, q4.z, q4.w};
#pragma unroll
        for (int d = 0; d < 4; ++d)
#pragma unroll
          for (int j = 0; j < 4; ++j) {
            int z = (int)((ds[d] >> (8 * j)) & 0xFFu);
            a += (z <= lane) ? 1 : 0;
          }
      }
      // LRU steps [64, A), 16-step groups with prefetch
      uint4 cur = zs4[4];
      for (int g = 4; g * 16 < A; ++g) {
        uint4 nxt = zs4[g + 1];  // +32 pad; overrun bytes never used
        const int gs = g * 16;
        unsigned int ds[4] = {cur.x, cur.y, cur.z, cur.w};
        if (gs + 16 <= wstart) {                     // MAIN: no e
#pragma unroll
          for (int d = 0; d < 4; ++d)
#pragma unroll
            for (int j = 0; j < 4; ++j) {
              int z = (int)((ds[d] >> (8 * j)) & 0xFFu);
              int xm1 = (z <= lane) ? 0 : -1;        // off-chain
              a = max(a, 1) + xm1;                   // 2-VALU chain
            }
        } else if (gs >= wstart && gs + 16 <= A) {   // WIN: e pre-update
#pragma unroll
          for (int d = 0; d < 4; ++d)
#pragma unroll
            for (int j = 0; j < 4; ++j) {
              int z = (int)((ds[d] >> (8 * j)) & 0xFFu);
              int xm1 = (z <= lane) ? 0 : -1;
              e += (a > 0) ? 1 : 0;
              a = max(a, 1) + xm1;
            }
        } else {                                     // GATED boundary
#pragma unroll
          for (int d = 0; d < 4; ++d)
#pragma unroll
            for (int j = 0; j < 4; ++j) {
              int i = gs + d * 4 + j;
              int z = (int)((ds[d] >> (8 * j)) & 0xFFu);
              int xm1 = (z <= lane) ? 0 : -1;
              bool vld = i < A;
              bool cg = (i >= wstart) && vld;
              e += (cg && a > 0) ? 1 : 0;
              int an = max(a, 1) + xm1;
              a = vld ? an : a;
            }
        }
        cur = nxt;
      }
    } else {
      for (int i = 0; i < A; ++i) {
        int z = zsB[i];
        a += (z <= lane) ? 1 : 0;
      }
    }

    int ap = __shfl_up(a, 1); if (lane == 0) ap = 0;
    int ep = __shfl_up(e, 1); if (lane == 0) ep = 0;
    cntTok[invS[lane]] = (a - ap) + (e - ep);
    if (lane == 0) { usedSh = fillN + win; susedSh = win; }
  } else if (tid < 192) {
    // ---- waves 1-2: q columns j0 and j0+128, interleaved (8 loads/4k) ----
    const int j0 = tid - 64;        // 0..127
    const int j1 = j0 + 128;        // 128..255
    const float* eL = &embS[lastv * EPAD];
    float a0 = 0, b0 = 0, a1 = 0, b1 = 0;
#pragma unroll 2
    for (int k = 0; k < HIDD; k += 4) {
      float e0 = eL[k], e1 = eL[k + 1], e2 = eL[k + 2], e3 = eL[k + 3];
      const float* w = &Wq[k * HIDD];
      a0 += e0 * w[j0];            a1 += e0 * w[j1];
      b0 += e1 * w[HIDD + j0];     b1 += e1 * w[HIDD + j1];
      a0 += e2 * w[2 * HIDD + j0]; a1 += e2 * w[2 * HIDD + j1];
      b0 += e3 * w[3 * HIDD + j0]; b1 += e3 * w[3 * HIDD + j1];
    }
    qS[j0] = a0 + b0 + bq[j0];
    qS[j1] = a1 + b1 + bq[j1];
  } else {
    // ---- wave 3: Wo -> LDS (float4) ----
    const float4* Wo4 = (const float4*)Wo;
    float4* WoS4 = (float4*)WoS;
    for (int i = tid - 192; i < HIDD * VOC / 4; i += 64) WoS4[i] = Wo4[i];
  }
  __syncthreads();

  // ---- P5: scores sc[v] = emb[v].q, then softmax regroup over counts ----
  {
    int v = tid & 63, part = tid >> 6;
    const float* er = &embS[v * EPAD + part * 64];
    const float* qr = &qS[part * 64];
    float s = 0.f;
#pragma unroll 8
    for (int k = 0; k < 64; ++k) s += er[k] * qr[k];
    pp[part][v] = s;
  }
  __syncthreads();
  if (tid < 64) {
    float sc = pp[0][tid] + pp[1][tid] + pp[2][tid] + pp[3][tid];
    int c = cntTok[tid];
    float m = (c > 0) ? sc : NEGC;
    for (int off = 32; off; off >>= 1) m = fmaxf(m, __shfl_xor(m, off));
    float w = (c > 0) ? (float)c * expf(sc - m) : 0.f;
    float z = w;
    for (int off = 32; off; off >>= 1) z += __shfl_xor(z, off);
    z += (float)(FASTN + SLOWN - usedSh) * expf(NEGC - m);  // 0 unless empty
    wS[tid] = w / z;
  }
  __syncthreads();

  // ---- P6: ctx[h] = sum_u wS[u] * emb[u][h] ----
  {
    float cacc = 0.f;
#pragma unroll 8
    for (int u = 0; u < 64; ++u) cacc += wS[u] * embS[u * EPAD + tid];
    ctxS[tid] = cacc;
  }
  __syncthreads();

  // ---- P7: logits = ctx @ Wo + bo ----
  {
    int o = tid & 63, part = tid >> 6;
    const float* cr = &ctxS[part * 64];
    const float* wr = &WoS[part * 64 * VOC + o];
    float s = 0.f;
#pragma unroll 8
    for (int k = 0; k < 64; ++k) s += cr[k] * wr[k * VOC];
    pp[part][o] = s;
  }
  __syncthreads();
  if (tid < 64)
    out[b * VOC + tid] = pp[0][tid] + pp[1][tid] + pp[2][tid] + pp[3][tid] + bo[tid];
  out[BB * VOC + b * SLOWN + tid] = (tid < susedSh) ? 1.0f : 0.0f;
}

// ---------------------------------------------------------------------------
extern "C" void kernel_launch(void* const* d_in, const int* in_sizes, int n_in,
                              void* d_out, int out_size, void* d_ws, size_t ws_size,
                              hipStream_t stream) {
  const int*   seq = (const int*)d_in[0];
  const float* emb = (const float*)d_in[1];
  const float* Wg  = (const float*)d_in[2];
  const float* bg  = (const float*)d_in[3];
  const float* Wd  = (const float*)d_in[4];
  const float* bd  = (const float*)d_in[5];
  const float* Wq  = (const float*)d_in[6];
  const float* bq  = (const float*)d_in[7];
  const float* Wo  = (const float*)d_in[8];
  const float* bo  = (const float*)d_in[9];
  float* out = (float*)d_out;

  k_all<<<dim3(64), dim3(256), 0, stream>>>(seq, emb, Wg, bg, Wd, bd,
                                            Wq, bq, Wo, bo, out);
}